// Round 3
// 513.070 us; speedup vs baseline: 1.0084x; 1.0084x over previous
//
#include <hip/hip_runtime.h>

// Problem constants (B=8, G=1024, K=32, C=168, OUT_DIM=336)
#define NGQ 1024
#define NKQ 32
#define NCQ 168
#define NOUTC 336
#define NXF 44040192       // B*G*K*C
#define NXYZQ 786432       // B*G*K*3
#define EPSV 1e-5f
#define PIO2 1.5707963267948966f
#define L2A_OVER_FD 0.17796043436f   // log2(1000)/56

#define NPART_X 1024
#define NPART_3 32
#define NPART (NPART_X + NPART_3)

#define GRID 512           // persistent main blocks (2/CU resident)
#define TPB 512
#define NPAIR 4096         // (B*G)/2 tile-pairs
#define TSTR 169           // padded c-stride per k-row (conflict-free reads)
#define TILEF (NKQ * TSTR) // 5408 floats per tile

// ---------------- Pass 1: partial sums for the two global stds ----------------
// (verbatim from the harness-verified baseline)
__global__ __launch_bounds__(256) void reduce_kernel(
    const float* __restrict__ knn_x, const float* __restrict__ lc_x,
    const float* __restrict__ knn_xyz, const float* __restrict__ lc_xyz,
    float4* __restrict__ part)
{
    float s = 0.f, q = 0.f, s3 = 0.f, q3 = 0.f;
    const int blk = blockIdx.x;
    const int tid = threadIdx.x;

    if (blk < NPART_X) {
        const float4* __restrict__ x4 = (const float4*)knn_x;
        const int n4 = NXF / 4;                     // 11,010,048
        for (int i = blk * 256 + tid; i < n4; i += NPART_X * 256) {
            float4 v = x4[i];
            int bg  = i / 1344;                     // float4s per (b,g) row-block
            int c4  = i - bg * 1344;
            int r42 = c4 % 42;                      // float4s per c-row (168/4)
            float4 l = *(const float4*)(lc_x + (size_t)bg * NCQ + r42 * 4);
            float dx = v.x - l.x, dy = v.y - l.y, dz = v.z - l.z, dw = v.w - l.w;
            s += (dx + dy) + (dz + dw);
            q = fmaf(dx, dx, q); q = fmaf(dy, dy, q);
            q = fmaf(dz, dz, q); q = fmaf(dw, dw, q);
        }
    } else {
        for (int i = (blk - NPART_X) * 256 + tid; i < NXYZQ; i += NPART_3 * 256) {
            float v = knn_xyz[i];
            int bg = i / 96;                        // K*3
            int j  = i % 3;
            float d = v - lc_xyz[bg * 3 + j];
            s3 += d;
            q3 = fmaf(d, d, q3);
        }
    }

    for (int off = 32; off; off >>= 1) {
        s  += __shfl_down(s,  off);
        q  += __shfl_down(q,  off);
        s3 += __shfl_down(s3, off);
        q3 += __shfl_down(q3, off);
    }
    __shared__ float red[4][4];
    int wv = tid >> 6;
    if ((tid & 63) == 0) { red[wv][0] = s; red[wv][1] = q; red[wv][2] = s3; red[wv][3] = q3; }
    __syncthreads();
    if (tid == 0) {
        part[blk] = make_float4(red[0][0] + red[1][0] + red[2][0] + red[3][0],
                                red[0][1] + red[1][1] + red[2][1] + red[3][1],
                                red[0][2] + red[1][2] + red[2][2] + red[3][2],
                                red[0][3] + red[1][3] + red[2][3] + red[3][3]);
    }
}

// ---------------- Pass 2: redundant finalize + fused main ----------------
// 512 persistent blocks x 512 threads. Every block deterministically reduces
// the same `part` buffer in the same order -> identical s_inv in all blocks.
// Then 8 tile-pairs per block: each wave64 nt-store is one 256B contiguous
// chunk (one c-plane x 2g x 32k).
__global__ __launch_bounds__(TPB, 4) void main_kernel(
    const float* __restrict__ lc_xyz, const float* __restrict__ lc_x,
    const float* __restrict__ knn_xyz, const float* __restrict__ knn_x,
    const float4* __restrict__ part, float* __restrict__ out)
{
    __shared__ float  s_x[2 * TILEF];        // 43,264 B: two raw knn_x tiles
    __shared__ float4 s_cc[2 * NOUTC];       // 10,752 B: {scale, phase, pe_lc, lc_x}
    __shared__ float  s_emb[2 * NKQ * 7];    //  1,792 B: per-k {xn0..2, cross, dot}
    __shared__ float2 s_so[NOUTC];           //  2,688 B: {scale, off} (pair-invariant)
    __shared__ float  s_lc[6];
    __shared__ double redd[8][4];
    __shared__ float  s_inv[2];

    const int tid = threadIdx.x;
    const int wv  = tid >> 6;

    // ---- redundant finalize (identical order in every block => deterministic)
    {
        double sd = 0.0, qd = 0.0, s3d = 0.0, q3d = 0.0;
        for (int i = tid; i < NPART; i += TPB) {
            float4 p = part[i];
            sd += p.x; qd += p.y; s3d += p.z; q3d += p.w;
        }
        for (int off = 32; off; off >>= 1) {
            sd  += __shfl_down(sd,  off);  qd  += __shfl_down(qd,  off);
            s3d += __shfl_down(s3d, off);  q3d += __shfl_down(q3d, off);
        }
        if ((tid & 63) == 0) { redd[wv][0]=sd; redd[wv][1]=qd; redd[wv][2]=s3d; redd[wv][3]=q3d; }
        __syncthreads();
        if (tid == 0) {
            double S=0,Q=0,S3=0,Q3=0;
            for (int w = 0; w < 8; ++w) { S+=redd[w][0]; Q+=redd[w][1]; S3+=redd[w][2]; Q3+=redd[w][3]; }
            double varx = (Q  - S  * S  / (double)NXF)   / (double)(NXF - 1);
            double var3 = (Q3 - S3 * S3 / (double)NXYZQ) / (double)(NXYZQ - 1);
            s_inv[0] = 1.0f / ((float)sqrt(varx) + EPSV);
            s_inv[1] = 1.0f / ((float)sqrt(var3) + EPSV);
        }
    }
    // per-channel {scale, off} table — pair-invariant, computed once per block
    for (int c = tid; c < NOUTC; c += TPB) {
        int dq = c / 112;
        int r  = c - dq * 112;
        int sf = (r >= 56);
        int f  = sf ? r - 56 : r;
        float scale = 100.f * exp2f(-L2A_OVER_FD * (float)f);  // 100/alpha^(f/56)
        s_so[c] = make_float2(scale, sf ? PIO2 : 0.f);         // cos = sin(+pi/2)
    }
    __syncthreads();
    const float inv_sx = s_inv[0];
    const float inv_s3 = s_inv[1];

    // ---- persistent pair loop ----
    const int c0  = tid >> 6;                 // 0..7: channel phase of this wave
    const int low = tid & 63;                 // gg*32 + k: contiguous store lane
    const int gg  = low >> 5;
    const int kq  = low & 31;
    const size_t STEPF = (size_t)8 << 15;     // 8 c-planes in floats

    for (int pp = blockIdx.x; pp < NPAIR; pp += GRID) {
        const size_t bg0 = (size_t)pp * 2;    // (b*1024 + g0)
        const int b  = pp >> 9;
        const int g0 = (pp & 511) << 1;

        __syncthreads();                      // prev phase C done before restage
        {
            const float4* __restrict__ src4 = (const float4*)(knn_x + bg0 * (NKQ * NCQ));
            for (int i = tid; i < 2688; i += TPB) {
                float4 v = src4[i];
                int t   = (i >= 1344);
                int rem = i - t * 1344;
                int kk  = rem / 42;
                int c4  = rem - kk * 42;
                float* dst = s_x + t * TILEF + kk * TSTR + c4 * 4;
                dst[0]=v.x; dst[1]=v.y; dst[2]=v.z; dst[3]=v.w;
            }
            if (tid < 6) s_lc[tid] = lc_xyz[bg0 * 3 + tid];
        }
        __syncthreads();

        if (tid < 64) {                       // per-k geometry, both tiles
            int t = tid >> 5, k = tid & 31;
            float b0=s_lc[t*3+0], b1=s_lc[t*3+1], b2=s_lc[t*3+2];
            const float* kx = knn_xyz + (bg0 + t) * (NKQ * 3) + k * 3;
            float a0=(kx[0]-b0)*inv_s3, a1=(kx[1]-b1)*inv_s3, a2=(kx[2]-b2)*inv_s3;
            float* e = s_emb + t * (NKQ * 7) + k * 7;
            e[0]=a0; e[1]=a1; e[2]=a2;
            e[3]=a1*b2 - a2*b1;               // cross(knn_xyz_n, lc)
            e[4]=a2*b0 - a0*b2;
            e[5]=a0*b1 - a1*b0;
            e[6]=a0*b0 + a1*b1 + a2*b2;       // dot
        }
        for (int i = tid; i < 2 * NOUTC; i += TPB) {   // per-channel constants
            int t  = (i >= NOUTC);
            int c  = i - t * NOUTC;
            float2 so = s_so[c];
            int dq = c / 112;
            float pelc = __sinf(fmaf(s_lc[t*3 + dq], so.x, so.y));
            float lx   = (c < NCQ) ? lc_x[(bg0 + t) * NCQ + c] : 0.f;
            s_cc[t * NOUTC + c] = make_float4(so.x, so.y, pelc, lx);
        }
        __syncthreads();

        // phase C: wave64 = one c-plane x (2g x 32k) = one 256B chunk per store
        const float*  sx   = s_x   + gg * TILEF + kq * TSTR;
        const float*  se   = s_emb + gg * (NKQ * 7) + kq * 7;
        const float   xn0 = se[0], xn1 = se[1], xn2 = se[2];
        const float4* cc_t = s_cc + gg * NOUTC;
        float* op = out + (size_t)b * (NOUTC * NGQ * NKQ)
                        + ((size_t)g0 << 5) + low + ((size_t)c0 << 15);
        int c = c0;

#define BODY(WEXPR, TT) do { float4 cc = cc_t[c]; float w = (WEXPR); \
        float pe = __sinf(fmaf((TT), cc.x, cc.y)) + cc.z; \
        __builtin_nontemporal_store((w + pe) * pe, op); op += STEPF; c += 8; } while (0)

        // c = c0+8j: j<14 -> c<112 ; j<21 -> c<168 ; j<28 -> c<224  (branch-free)
        #pragma unroll
        for (int j = 0; j < 14; ++j) BODY((sx[c] - cc.w) * inv_sx, xn0);
        #pragma unroll
        for (int j = 0; j < 7;  ++j) BODY((sx[c] - cc.w) * inv_sx, xn1);
        int e7 = (c0 >= 7) ? c0 - 7 : c0;     // (c-168)%7; step 8 == +1 mod 7
        #pragma unroll
        for (int j = 0; j < 7;  ++j) { BODY(se[e7], xn1); e7 = (e7 == 6) ? 0 : e7 + 1; }
        #pragma unroll
        for (int j = 0; j < 14; ++j) { BODY(se[e7], xn2); e7 = (e7 == 6) ? 0 : e7 + 1; }
#undef BODY
    }
}

extern "C" void kernel_launch(void* const* d_in, const int* in_sizes, int n_in,
                              void* d_out, int out_size, void* d_ws, size_t ws_size,
                              hipStream_t stream) {
    const float* lc_xyz  = (const float*)d_in[0];
    const float* lc_x    = (const float*)d_in[1];
    const float* knn_xyz = (const float*)d_in[2];
    const float* knn_x   = (const float*)d_in[3];
    float* outp  = (float*)d_out;
    float4* part = (float4*)d_ws;             // NPART*16 B = 16.9 KB of workspace

    reduce_kernel<<<NPART, 256, 0, stream>>>(knn_x, lc_x, knn_xyz, lc_xyz, part);
    main_kernel<<<GRID, TPB, 0, stream>>>(lc_xyz, lc_x, knn_xyz, knn_x, part, outp);
}